// Round 4
// baseline (362.663 us; speedup 1.0000x reference)
//
#include <hip/hip_runtime.h>
#include <cstddef>

#define BATCH   2
#define SEQ     2048
#define DMODEL  1024
#define NH      16
#define HDIM    64
#define WIN     256
#define MTOT    4096
#define QKLD    2048   // qkvh row stride (Q,K cols only)
#define QLLD    1024   // qkvl row stride (Q cols only)
#define VTLD    4096   // Vt row stride (keys)

typedef __bf16 bf16;
typedef __attribute__((ext_vector_type(8)))  __bf16 bf16x8;
typedef __attribute__((ext_vector_type(4)))  float  f32x4;
typedef __attribute__((ext_vector_type(16))) float  f32x16;

#define GLOAD_LDS(gp, lp) __builtin_amdgcn_global_load_lds( \
    (const __attribute__((address_space(1))) void*)(gp),    \
    (__attribute__((address_space(3))) void*)(lp), 16, 0, 0)

// ---------------------------------------------------------------------------
// Merged pre-pass: split x, w1, w2 into bf16 hi/lo in one launch.
// ---------------------------------------------------------------------------
__global__ __launch_bounds__(256)
void cvt_all(const float* __restrict__ x, const float* __restrict__ w1,
             const float* __restrict__ w2, bf16* __restrict__ xh,
             bf16* __restrict__ xl, bf16* __restrict__ w1h,
             bf16* __restrict__ w1l, bf16* __restrict__ w2h,
             bf16* __restrict__ w2l) {
  const int bid = blockIdx.x;
  const float* s; bf16 *hp, *lp; int base;
  if (bid < 2048)      { s = x;  hp = xh;  lp = xl;  base = bid * 2048; }
  else if (bid < 3584) { s = w1; hp = w1h; lp = w1l; base = (bid - 2048) * 2048; }
  else                 { s = w2; hp = w2h; lp = w2l; base = (bid - 3584) * 2048; }
  const int i = base + threadIdx.x * 8;
  float4 a = *(const float4*)(s + i);
  float4 c = *(const float4*)(s + i + 4);
  const float f[8] = {a.x, a.y, a.z, a.w, c.x, c.y, c.z, c.w};
  bf16x8 vh, vl;
#pragma unroll
  for (int j = 0; j < 8; ++j) {
    bf16 hh = (bf16)f[j];
    vh[j] = hh;
    vl[j] = (bf16)(f[j] - (float)hh);
  }
  *(bf16x8*)(hp + i) = vh;
  *(bf16x8*)(lp + i) = vl;
}

// ---------------------------------------------------------------------------
// Split-bf16 MFMA GEMM, m97 structure. C = (Ah+Al)(Bh+Bl)^T + bias.
// Output modes: Cf -> fp32; else Ch (hi, ld N) + optional Cl (lo, ld locols,
// cols < locols). bias_rows: bias indexed by output row (for V^T gemm).
// ---------------------------------------------------------------------------
__global__ __launch_bounds__(256)
void gemm_split(const bf16* __restrict__ Ah, const bf16* __restrict__ Al,
                const bf16* __restrict__ Bh, const bf16* __restrict__ Bl,
                const float* __restrict__ bias, int K, int N,
                float* __restrict__ Cf, bf16* __restrict__ Ch,
                bf16* __restrict__ Cl, int locols, int bias_rows) {
  __shared__ bf16 sAh[128 * 32];
  __shared__ bf16 sAl[128 * 32];
  __shared__ bf16 sBh[128 * 32];
  __shared__ bf16 sBl[128 * 32];

  const int t = threadIdx.x, w = t >> 6, lane = t & 63;
  const int ln15 = lane & 15, quad = lane >> 4;
  const int bm = blockIdx.y * 128, bn = blockIdx.x * 128;
  const int wrow = (w & 1) * 64, wcol = (w >> 1) * 64;
  const int drow = lane >> 2;
  const int dkcol = (lane & 3) * 8;

  f32x4 acc[4][4];
#pragma unroll
  for (int i = 0; i < 4; ++i)
#pragma unroll
    for (int j = 0; j < 4; ++j)
#pragma unroll
      for (int r = 0; r < 4; ++r) acc[i][j][r] = 0.f;

  for (int k0 = 0; k0 < K; k0 += 32) {
    __syncthreads();
#pragma unroll
    for (int half = 0; half < 2; ++half) {
      const int r = w * 32 + half * 16 + drow;
      const size_t goffA = (size_t)(bm + r) * K + k0 + dkcol;
      const size_t goffB = (size_t)(bn + r) * K + k0 + dkcol;
      const int loff = (w * 32 + half * 16) * 32;
      GLOAD_LDS(Ah + goffA, sAh + loff);
      GLOAD_LDS(Al + goffA, sAl + loff);
      GLOAD_LDS(Bh + goffB, sBh + loff);
      GLOAD_LDS(Bl + goffB, sBl + loff);
    }
    __syncthreads();

    bf16x8 afh[4], afl[4], bfh[4], bfl[4];
#pragma unroll
    for (int mt = 0; mt < 4; ++mt) {
      const int off = (wrow + mt * 16 + ln15) * 32 + quad * 8;
      afh[mt] = *(const bf16x8*)&sAh[off];
      afl[mt] = *(const bf16x8*)&sAl[off];
    }
#pragma unroll
    for (int nt = 0; nt < 4; ++nt) {
      const int off = (wcol + nt * 16 + ln15) * 32 + quad * 8;
      bfh[nt] = *(const bf16x8*)&sBh[off];
      bfl[nt] = *(const bf16x8*)&sBl[off];
    }
#pragma unroll
    for (int mt = 0; mt < 4; ++mt)
#pragma unroll
      for (int nt = 0; nt < 4; ++nt) {
        acc[mt][nt] = __builtin_amdgcn_mfma_f32_16x16x32_bf16(afh[mt], bfh[nt], acc[mt][nt], 0, 0, 0);
        acc[mt][nt] = __builtin_amdgcn_mfma_f32_16x16x32_bf16(afh[mt], bfl[nt], acc[mt][nt], 0, 0, 0);
        acc[mt][nt] = __builtin_amdgcn_mfma_f32_16x16x32_bf16(afl[mt], bfh[nt], acc[mt][nt], 0, 0, 0);
      }
  }

  float bbcol[4];
#pragma unroll
  for (int nt = 0; nt < 4; ++nt) bbcol[nt] = bias_rows ? 0.f : bias[bn + wcol + nt * 16 + ln15];

#pragma unroll
  for (int mt = 0; mt < 4; ++mt)
#pragma unroll
    for (int r = 0; r < 4; ++r) {
      const size_t grow = (size_t)(bm + wrow + mt * 16 + quad * 4 + r);
      const float brow = bias_rows ? bias[grow] : 0.f;
#pragma unroll
      for (int nt = 0; nt < 4; ++nt) {
        const int col = bn + wcol + nt * 16 + ln15;
        const float v = acc[mt][nt][r] + bbcol[nt] + brow;
        if (Cf) {
          Cf[grow * N + col] = v;
        } else {
          const bf16 hh = (bf16)v;
          Ch[grow * N + col] = hh;
          if (Cl && col < locols) Cl[grow * locols + col] = (bf16)(v - (float)hh);
        }
      }
    }
}

// ---------------------------------------------------------------------------
// MFMA flash attention. Allowed keys: j <= i + WIN.
// Block = (b,h) x 128-query tile (4 waves x 32 rows); 64-key tiles.
// Q split hi/lo (loaded once, scale folded); K hi-only; V^T pre-computed.
// Double-buffered K/V staging via frag-ordered global_load_lds (separate
// __shared__ arrays + uniform parity branch so alias analysis can't pin
// vmcnt). No-max softmax: p = exp2(s), s pre-scaled by log2e/8, clamp 60.
// Row-sum l via ones-column MFMA. Complementary-pair grid swizzle balances
// the causal-window tail (bid and bid+256 sum to ~uniform work).
// ---------------------------------------------------------------------------
__global__ __launch_bounds__(256)
void attn_mfma(const bf16* __restrict__ qkvh, const bf16* __restrict__ qkvl,
               const bf16* __restrict__ Vt,
               bf16* __restrict__ Omh, bf16* __restrict__ Oml) {
  const int t = threadIdx.x, w = t >> 6, lane = t & 63;
  const int ln31 = lane & 31, half = lane >> 5;
  const int bid = blockIdx.x;
  const int p = bid >> 8, r0 = bid & 255;
  const int bh = (r0 >> 4) + (p << 4);
  const int qt = p ? (15 - (r0 & 15)) : (r0 & 15);
  const int i0 = qt * 128;
  const int b = bh >> 4, h = bh & 15;
  const int colK = DMODEL + h * 64;

  __shared__ bf16 sKA[8 * 64 * 8];
  __shared__ bf16 sKB[8 * 64 * 8];
  __shared__ bf16 sVA[8 * 64 * 8];
  __shared__ bf16 sVB[8 * 64 * 8];
  __shared__ bf16 sP[128 * 72];

  // ---- Q fragments: hi+lo combined, scaled by log2(e)/8, re-split ----
  bf16x8 qh[4], ql[4];
  {
    const size_t rowQ = (size_t)(b * SEQ + i0 + w * 32 + ln31);
#pragma unroll
    for (int ks = 0; ks < 4; ++ks) {
      bf16x8 vh = *(const bf16x8*)(qkvh + rowQ * QKLD + h * 64 + ks * 16 + half * 8);
      bf16x8 vl = *(const bf16x8*)(qkvl + rowQ * QLLD + h * 64 + ks * 16 + half * 8);
#pragma unroll
      for (int j = 0; j < 8; ++j) {
        float f = ((float)vh[j] + (float)vl[j]) * 0.1803368801111204f;  // log2(e)/8
        bf16 hh = (bf16)f;
        qh[ks][j] = hh;
        ql[ks][j] = (bf16)(f - (float)hh);
      }
    }
  }
  bf16x8 onesf;
#pragma unroll
  for (int j = 0; j < 8; ++j) onesf[j] = (ln31 == 0) ? (bf16)1.0f : (bf16)0.0f;

  f32x16 accO0, accO1, accL;
#pragma unroll
  for (int r = 0; r < 16; ++r) { accO0[r] = 0.f; accO1[r] = 0.f; accL[r] = 0.f; }

  // waves 0,1 stage K (slots 0..7), waves 2,3 stage V (slots 0..7)
  auto stage = [&](int kt, bf16* Kb, bf16* Vb) {
    const int j0s = kt * 64;
#pragma unroll
    for (int ii = 0; ii < 4; ++ii) {
      const int s = w * 4 + ii;
      if (s < 8) {
        const int c = s >> 2, ks = s & 3;
        const size_t gr = (size_t)(b * SEQ + j0s + c * 32 + ln31);
        GLOAD_LDS(qkvh + gr * QKLD + colK + ks * 16 + half * 8, Kb + s * 512);
      } else {
        const int cs = s - 8, cn = cs >> 2, ks = cs & 3;
        const size_t vr = (size_t)(h * 64 + cn * 32 + ln31);
        GLOAD_LDS(Vt + vr * VTLD + b * SEQ + j0s + ks * 16 + half * 8, Vb + cs * 512);
      }
    }
  };

  auto compute = [&](const bf16* Kb, const bf16* Vb, int j0) {
    // ---- S = Q K^T (Q split: hh + lh) ----
    f32x16 S0, S1;
#pragma unroll
    for (int r = 0; r < 16; ++r) { S0[r] = 0.f; S1[r] = 0.f; }
#pragma unroll
    for (int ks = 0; ks < 4; ++ks) {
      bf16x8 k0 = *(const bf16x8*)&Kb[((0 * 4 + ks) * 64 + lane) * 8];
      bf16x8 k1 = *(const bf16x8*)&Kb[((1 * 4 + ks) * 64 + lane) * 8];
      S0 = __builtin_amdgcn_mfma_f32_32x32x16_bf16(qh[ks], k0, S0, 0, 0, 0);
      S0 = __builtin_amdgcn_mfma_f32_32x32x16_bf16(ql[ks], k0, S0, 0, 0, 0);
      S1 = __builtin_amdgcn_mfma_f32_32x32x16_bf16(qh[ks], k1, S1, 0, 0, 0);
      S1 = __builtin_amdgcn_mfma_f32_32x32x16_bf16(ql[ks], k1, S1, 0, 0, 0);
    }

    // ---- mask, exp2, write P (bf16) to LDS row-major ----
#pragma unroll
    for (int c = 0; c < 2; ++c) {
      f32x16& S = c ? S1 : S0;
      const int jg = j0 + c * 32 + ln31;
      const bool may = (j0 + c * 32 + 31) > (i0 + w * 32 + WIN);
#pragma unroll
      for (int r = 0; r < 16; ++r) {
        const int rl = (r & 3) + 8 * (r >> 2) + 4 * half;
        float sv = S[r];
        if (may && (jg > i0 + w * 32 + rl + WIN)) sv = -1e30f;
        sv = exp2f(fminf(sv, 60.f));
        sP[(w * 32 + rl) * 72 + c * 32 + ln31] = (bf16)sv;
      }
    }

    // ---- O += P V ; l += P 1  (wave-local P) ----
#pragma unroll
    for (int ks = 0; ks < 4; ++ks) {
      bf16x8 pA = *(const bf16x8*)&sP[(w * 32 + ln31) * 72 + ks * 16 + half * 8];
      bf16x8 v0 = *(const bf16x8*)&Vb[((0 * 4 + ks) * 64 + lane) * 8];
      bf16x8 v1 = *(const bf16x8*)&Vb[((1 * 4 + ks) * 64 + lane) * 8];
      accO0 = __builtin_amdgcn_mfma_f32_32x32x16_bf16(pA, v0, accO0, 0, 0, 0);
      accO1 = __builtin_amdgcn_mfma_f32_32x32x16_bf16(pA, v1, accO1, 0, 0, 0);
      accL  = __builtin_amdgcn_mfma_f32_32x32x16_bf16(pA, onesf, accL, 0, 0, 0);
    }
  };

  const int nkt = min(2 * qt + 6, SEQ / 64);
  stage(0, sKA, sVA);
  for (int kt = 0; kt < nkt; ++kt) {
    __syncthreads();   // drains prior DMA (vmcnt) + frees other buffer
    const bool pa = !(kt & 1);
    if (kt + 1 < nkt) {
      if (pa) stage(kt + 1, sKB, sVB); else stage(kt + 1, sKA, sVA);
    }
    const int j0 = kt * 64;
    if (j0 <= i0 + w * 32 + 31 + WIN) {   // wave-uniform tail skip
      if (pa) compute(sKA, sVA, j0); else compute(sKB, sVB, j0);
    }
  }

  // ---- epilogue: O /= l, write Om hi/lo ----
#pragma unroll
  for (int r = 0; r < 16; ++r) {
    const int rl = (r & 3) + 8 * (r >> 2) + 4 * half;
    const float lv = __shfl(accL[r], lane & 32, 64);
    const float inv = 1.0f / lv;
    const size_t grow = (size_t)(b * SEQ + i0 + w * 32 + rl);
    const int col0 = h * 64 + ln31;
    const float v0 = accO0[r] * inv;
    const float v1 = accO1[r] * inv;
    const bf16 h0 = (bf16)v0, h1 = (bf16)v1;
    Omh[grow * DMODEL + col0]      = h0;
    Oml[grow * DMODEL + col0]      = (bf16)(v0 - (float)h0);
    Omh[grow * DMODEL + col0 + 32] = h1;
    Oml[grow * DMODEL + col0 + 32] = (bf16)(v1 - (float)h1);
  }
}

// ---------------------------------------------------------------------------
extern "C" void kernel_launch(void* const* d_in, const int* in_sizes, int n_in,
                              void* d_out, int out_size, void* d_ws, size_t ws_size,
                              hipStream_t stream) {
  const float* x  = (const float*)d_in[0];
  const float* w1 = (const float*)d_in[1];
  const float* b1 = (const float*)d_in[2];
  const float* w2 = (const float*)d_in[3];
  const float* b2 = (const float*)d_in[4];
  float* out = (float*)d_out;

  char* ws = (char*)d_ws;
  bf16* qkvh = (bf16*)(ws + 0);          // [4096][2048]  Q,K hi
  bf16* qkvl = (bf16*)(ws + 16777216);   // [4096][1024]  Q lo
  bf16* Vt   = (bf16*)(ws + 25165824);   // [1024][4096]  V^T hi
  bf16* xh   = (bf16*)(ws + 33554432);   // [4096][1024]
  bf16* xl   = (bf16*)(ws + 41943040);
  bf16* w1h  = (bf16*)(ws + 50331648);   // [3072][1024]
  bf16* w1l  = (bf16*)(ws + 56623104);
  bf16* w2h  = (bf16*)(ws + 62914560);   // [1024][1024]
  bf16* w2l  = (bf16*)(ws + 65011712);
  bf16* Omh  = xh;                       // reuse (x split dead after V^T gemm)
  bf16* Oml  = xl;

  cvt_all<<<dim3(4096), 256, 0, stream>>>(x, w1, w2, xh, xl, w1h, w1l, w2h, w2l);

  // Q,K = x @ w1[0:2048]^T + b1[0:2048]  -> hi (ld 2048) + lo (Q cols only)
  gemm_split<<<dim3(QKLD / 128, MTOT / 128), 256, 0, stream>>>(
      xh, xl, w1h, w1l, b1, DMODEL, QKLD, nullptr, qkvh, qkvl, QLLD, 0);

  // V^T = w1[2048:3072] @ x^T + b1[2048:] (per-row bias) -> hi only
  gemm_split<<<dim3(MTOT / 128, DMODEL / 128), 256, 0, stream>>>(
      w1h + 2048 * 1024, w1l + 2048 * 1024, xh, xl, b1 + 2048,
      DMODEL, MTOT, nullptr, Vt, nullptr, 0, 1);

  attn_mfma<<<dim3(512), 256, 0, stream>>>(qkvh, qkvl, Vt, Omh, Oml);

  // out = Om @ w2^T + b2 (fp32)
  gemm_split<<<dim3(DMODEL / 128, MTOT / 128), 256, 0, stream>>>(
      Omh, Oml, w2h, w2l, b2, DMODEL, DMODEL, out, nullptr, nullptr, 0, 0);
}

// Round 5
// 338.574 us; speedup vs baseline: 1.0711x; 1.0711x over previous
//
#include <hip/hip_runtime.h>
#include <cstddef>

#define BATCH   2
#define SEQ     2048
#define DMODEL  1024
#define NH      16
#define HDIM    64
#define WIN     256
#define MTOT    4096
#define QKLD    2048   // qkvh row stride (Q,K cols only)
#define QLLD    1024   // qkvl row stride (Q cols only)
#define VTLD    4096   // Vt row stride (keys)

typedef __bf16 bf16;
typedef __attribute__((ext_vector_type(8)))  __bf16 bf16x8;
typedef __attribute__((ext_vector_type(4)))  float  f32x4;
typedef __attribute__((ext_vector_type(16))) float  f32x16;

#define GLOAD_LDS(gp, lp) __builtin_amdgcn_global_load_lds( \
    (const __attribute__((address_space(1))) void*)(gp),    \
    (__attribute__((address_space(3))) void*)(lp), 16, 0, 0)

__device__ __forceinline__ float fast_exp2(float x) {
#if __has_builtin(__builtin_amdgcn_exp2f)
  return __builtin_amdgcn_exp2f(x);
#else
  float r; asm("v_exp_f32 %0, %1" : "=v"(r) : "v"(x)); return r;
#endif
}

// ---------------------------------------------------------------------------
// Merged pre-pass: split x, w1, w2 into bf16 hi/lo in one launch.
// ---------------------------------------------------------------------------
__global__ __launch_bounds__(256)
void cvt_all(const float* __restrict__ x, const float* __restrict__ w1,
             const float* __restrict__ w2, bf16* __restrict__ xh,
             bf16* __restrict__ xl, bf16* __restrict__ w1h,
             bf16* __restrict__ w1l, bf16* __restrict__ w2h,
             bf16* __restrict__ w2l) {
  const int bid = blockIdx.x;
  const float* s; bf16 *hp, *lp; int base;
  if (bid < 2048)      { s = x;  hp = xh;  lp = xl;  base = bid * 2048; }
  else if (bid < 3584) { s = w1; hp = w1h; lp = w1l; base = (bid - 2048) * 2048; }
  else                 { s = w2; hp = w2h; lp = w2l; base = (bid - 3584) * 2048; }
  const int i = base + threadIdx.x * 8;
  float4 a = *(const float4*)(s + i);
  float4 c = *(const float4*)(s + i + 4);
  const float f[8] = {a.x, a.y, a.z, a.w, c.x, c.y, c.z, c.w};
  bf16x8 vh, vl;
#pragma unroll
  for (int j = 0; j < 8; ++j) {
    bf16 hh = (bf16)f[j];
    vh[j] = hh;
    vl[j] = (bf16)(f[j] - (float)hh);
  }
  *(bf16x8*)(hp + i) = vh;
  *(bf16x8*)(lp + i) = vl;
}

// ---------------------------------------------------------------------------
// Split-bf16 MFMA GEMM, m97 structure. C = (Ah+Al)(Bh+Bl)^T + bias.
// Output modes: Cf -> fp32; else Ch (hi, ld N) + optional Cl (lo, ld locols,
// cols < locols). bias_rows: bias indexed by output row (for V^T gemm).
// ---------------------------------------------------------------------------
__global__ __launch_bounds__(256)
void gemm_split(const bf16* __restrict__ Ah, const bf16* __restrict__ Al,
                const bf16* __restrict__ Bh, const bf16* __restrict__ Bl,
                const float* __restrict__ bias, int K, int N,
                float* __restrict__ Cf, bf16* __restrict__ Ch,
                bf16* __restrict__ Cl, int locols, int bias_rows) {
  __shared__ bf16 sAh[128 * 32];
  __shared__ bf16 sAl[128 * 32];
  __shared__ bf16 sBh[128 * 32];
  __shared__ bf16 sBl[128 * 32];

  const int t = threadIdx.x, w = t >> 6, lane = t & 63;
  const int ln15 = lane & 15, quad = lane >> 4;
  const int bm = blockIdx.y * 128, bn = blockIdx.x * 128;
  const int wrow = (w & 1) * 64, wcol = (w >> 1) * 64;
  const int drow = lane >> 2;
  const int dkcol = (lane & 3) * 8;

  f32x4 acc[4][4];
#pragma unroll
  for (int i = 0; i < 4; ++i)
#pragma unroll
    for (int j = 0; j < 4; ++j)
#pragma unroll
      for (int r = 0; r < 4; ++r) acc[i][j][r] = 0.f;

  for (int k0 = 0; k0 < K; k0 += 32) {
    __syncthreads();
#pragma unroll
    for (int half = 0; half < 2; ++half) {
      const int r = w * 32 + half * 16 + drow;
      const size_t goffA = (size_t)(bm + r) * K + k0 + dkcol;
      const size_t goffB = (size_t)(bn + r) * K + k0 + dkcol;
      const int loff = (w * 32 + half * 16) * 32;
      GLOAD_LDS(Ah + goffA, sAh + loff);
      GLOAD_LDS(Al + goffA, sAl + loff);
      GLOAD_LDS(Bh + goffB, sBh + loff);
      GLOAD_LDS(Bl + goffB, sBl + loff);
    }
    __syncthreads();

    bf16x8 afh[4], afl[4], bfh[4], bfl[4];
#pragma unroll
    for (int mt = 0; mt < 4; ++mt) {
      const int off = (wrow + mt * 16 + ln15) * 32 + quad * 8;
      afh[mt] = *(const bf16x8*)&sAh[off];
      afl[mt] = *(const bf16x8*)&sAl[off];
    }
#pragma unroll
    for (int nt = 0; nt < 4; ++nt) {
      const int off = (wcol + nt * 16 + ln15) * 32 + quad * 8;
      bfh[nt] = *(const bf16x8*)&sBh[off];
      bfl[nt] = *(const bf16x8*)&sBl[off];
    }
#pragma unroll
    for (int mt = 0; mt < 4; ++mt)
#pragma unroll
      for (int nt = 0; nt < 4; ++nt) {
        acc[mt][nt] = __builtin_amdgcn_mfma_f32_16x16x32_bf16(afh[mt], bfh[nt], acc[mt][nt], 0, 0, 0);
        acc[mt][nt] = __builtin_amdgcn_mfma_f32_16x16x32_bf16(afh[mt], bfl[nt], acc[mt][nt], 0, 0, 0);
        acc[mt][nt] = __builtin_amdgcn_mfma_f32_16x16x32_bf16(afl[mt], bfh[nt], acc[mt][nt], 0, 0, 0);
      }
  }

  float bbcol[4];
#pragma unroll
  for (int nt = 0; nt < 4; ++nt) bbcol[nt] = bias_rows ? 0.f : bias[bn + wcol + nt * 16 + ln15];

#pragma unroll
  for (int mt = 0; mt < 4; ++mt)
#pragma unroll
    for (int r = 0; r < 4; ++r) {
      const size_t grow = (size_t)(bm + wrow + mt * 16 + quad * 4 + r);
      const float brow = bias_rows ? bias[grow] : 0.f;
#pragma unroll
      for (int nt = 0; nt < 4; ++nt) {
        const int col = bn + wcol + nt * 16 + ln15;
        const float v = acc[mt][nt][r] + bbcol[nt] + brow;
        if (Cf) {
          Cf[grow * N + col] = v;
        } else {
          const bf16 hh = (bf16)v;
          Ch[grow * N + col] = hh;
          if (Cl && col < locols) Cl[grow * locols + col] = (bf16)(v - (float)hh);
        }
      }
    }
}

// ---------------------------------------------------------------------------
// MFMA flash attention, register-direct (no K/V LDS staging, NO barriers).
// Block = (b,h) x 128-query tile; 4 independent waves x 32 q-rows; 64-key
// tiles. K fragments are 8 contiguous bf16 of a qkvh row; V^T fragments are
// 8 contiguous bf16 of a Vt row -> plain global_load_dwordx4 into VGPRs.
// K double-buffered (next tile issued before softmax); V issued at iter top,
// consumed ~500cyc later. Softmax: p = v_exp_f32(s) (scale log2e/8 folded
// into Q), mask applied as p->0 cndmask AFTER exp (|s|<=~20, no overflow).
// P round-trips through wave-private LDS rows to reach A-frag layout.
// Row-sum l via ones-column MFMA. Complementary-pair swizzle for tail balance.
// ---------------------------------------------------------------------------
__global__ __launch_bounds__(256)
void attn_mfma(const bf16* __restrict__ qkvh, const bf16* __restrict__ qkvl,
               const bf16* __restrict__ Vt,
               bf16* __restrict__ Omh, bf16* __restrict__ Oml) {
  const int t = threadIdx.x, w = t >> 6, lane = t & 63;
  const int ln31 = lane & 31, half = lane >> 5;
  const int bid = blockIdx.x;
  const int p = bid >> 8, r0 = bid & 255;
  const int bh = (r0 >> 4) + (p << 4);
  const int qt = p ? (15 - (r0 & 15)) : (r0 & 15);
  const int i0 = qt * 128;
  const int b = bh >> 4, h = bh & 15;
  const int i0w = i0 + w * 32;                 // this wave's first q row
  const int lim = i0w + WIN;                   // allowed: j <= lim + rl

  __shared__ bf16 sP[128 * 72];                // wave-private rows

  // ---- Q fragments: hi+lo combined, scaled by log2(e)/8, re-split ----
  bf16x8 qh[4], ql[4];
  {
    const size_t rowQ = (size_t)(b * SEQ + i0w + ln31);
#pragma unroll
    for (int ks = 0; ks < 4; ++ks) {
      bf16x8 vh = *(const bf16x8*)(qkvh + rowQ * QKLD + h * 64 + ks * 16 + half * 8);
      bf16x8 vl = *(const bf16x8*)(qkvl + rowQ * QLLD + h * 64 + ks * 16 + half * 8);
#pragma unroll
      for (int j = 0; j < 8; ++j) {
        float f = ((float)vh[j] + (float)vl[j]) * 0.1803368801111204f;  // log2(e)/8
        bf16 hh = (bf16)f;
        qh[ks][j] = hh;
        ql[ks][j] = (bf16)(f - (float)hh);
      }
    }
  }
  bf16x8 onesf;
#pragma unroll
  for (int j = 0; j < 8; ++j) onesf[j] = (ln31 == 0) ? (bf16)1.0f : (bf16)0.0f;

  f32x16 accO0, accO1, accL;
#pragma unroll
  for (int r = 0; r < 16; ++r) { accO0[r] = 0.f; accO1[r] = 0.f; accL[r] = 0.f; }

  // per-wave K/V fragment base pointers (c in {0,1} x ks in 0..3)
  const bf16* Kbase = qkvh + (size_t)(b * SEQ + ln31) * QKLD + DMODEL + h * 64 + half * 8;
  const bf16* Vbase = Vt + (size_t)(h * 64 + ln31) * VTLD + b * SEQ + half * 8;

  const int nkt = min((i0w + 31 + WIN) / 64 + 1, SEQ / 64);   // per-wave tiles

  auto loadK = [&](int kt, bf16x8 (&K)[8]) {
    const size_t off = (size_t)(kt * 64) * QKLD;
#pragma unroll
    for (int c = 0; c < 2; ++c)
#pragma unroll
      for (int ks = 0; ks < 4; ++ks)
        K[c * 4 + ks] = *(const bf16x8*)(Kbase + off + (size_t)(c * 32) * QKLD + ks * 16);
  };

  auto iter = [&](int kt, bf16x8 (&Kc)[8], bf16x8 (&Kn)[8]) {
    const int j0 = kt * 64;
    // ---- issue V loads (consumed after softmax) ----
    bf16x8 V[8];
#pragma unroll
    for (int c = 0; c < 2; ++c)
#pragma unroll
      for (int ks = 0; ks < 4; ++ks)
        V[c * 4 + ks] = *(const bf16x8*)(Vbase + (size_t)(c * 32) * VTLD + j0 + ks * 16);

    // ---- S = Q K^T (Q split: hh + lh) ----
    f32x16 S0, S1;
#pragma unroll
    for (int r = 0; r < 16; ++r) { S0[r] = 0.f; S1[r] = 0.f; }
#pragma unroll
    for (int ks = 0; ks < 4; ++ks) {
      S0 = __builtin_amdgcn_mfma_f32_32x32x16_bf16(qh[ks], Kc[ks],     S0, 0, 0, 0);
      S0 = __builtin_amdgcn_mfma_f32_32x32x16_bf16(ql[ks], Kc[ks],     S0, 0, 0, 0);
      S1 = __builtin_amdgcn_mfma_f32_32x32x16_bf16(qh[ks], Kc[4 + ks], S1, 0, 0, 0);
      S1 = __builtin_amdgcn_mfma_f32_32x32x16_bf16(ql[ks], Kc[4 + ks], S1, 0, 0, 0);
    }

    // ---- prefetch next K tile (covered by softmax + PV) ----
    if (kt + 1 < nkt) loadK(kt + 1, Kn);

    // ---- softmax: p = exp2(s); mask -> 0 after exp; write P to LDS ----
#pragma unroll
    for (int c = 0; c < 2; ++c) {
      f32x16& S = c ? S1 : S0;
      const int vj = j0 + c * 32 + ln31 - lim;        // mask if vj > rl
      const bool may = (j0 + c * 32 + 31) > lim;
#pragma unroll
      for (int r = 0; r < 16; ++r) {
        const int rl = (r & 3) + 8 * (r >> 2) + 4 * half;
        float pv = fast_exp2(S[r]);
        if (may && (vj > rl)) pv = 0.f;
        sP[(w * 32 + rl) * 72 + c * 32 + ln31] = (bf16)pv;
      }
    }

    // ---- O += P V ; l += P 1  (wave-private P rows) ----
#pragma unroll
    for (int ks = 0; ks < 4; ++ks) {
      bf16x8 pA = *(const bf16x8*)&sP[(w * 32 + ln31) * 72 + ks * 16 + half * 8];
      accO0 = __builtin_amdgcn_mfma_f32_32x32x16_bf16(pA, V[ks],     accO0, 0, 0, 0);
      accO1 = __builtin_amdgcn_mfma_f32_32x32x16_bf16(pA, V[4 + ks], accO1, 0, 0, 0);
      accL  = __builtin_amdgcn_mfma_f32_32x32x16_bf16(pA, onesf,     accL,  0, 0, 0);
    }
  };

  bf16x8 KA[8], KB[8];
  loadK(0, KA);
  for (int kt = 0; kt < nkt; kt += 2) {
    iter(kt, KA, KB);
    if (kt + 1 < nkt) iter(kt + 1, KB, KA);
  }

  // ---- epilogue: O /= l, write Om hi/lo ----
#pragma unroll
  for (int r = 0; r < 16; ++r) {
    const int rl = (r & 3) + 8 * (r >> 2) + 4 * half;
    const float lv = __shfl(accL[r], lane & 32, 64);
    const float inv = 1.0f / lv;
    const size_t grow = (size_t)(b * SEQ + i0w + rl);
    const int col0 = h * 64 + ln31;
    const float v0 = accO0[r] * inv;
    const float v1 = accO1[r] * inv;
    const bf16 h0 = (bf16)v0, h1 = (bf16)v1;
    Omh[grow * DMODEL + col0]      = h0;
    Oml[grow * DMODEL + col0]      = (bf16)(v0 - (float)h0);
    Omh[grow * DMODEL + col0 + 32] = h1;
    Oml[grow * DMODEL + col0 + 32] = (bf16)(v1 - (float)h1);
  }
}

// ---------------------------------------------------------------------------
extern "C" void kernel_launch(void* const* d_in, const int* in_sizes, int n_in,
                              void* d_out, int out_size, void* d_ws, size_t ws_size,
                              hipStream_t stream) {
  const float* x  = (const float*)d_in[0];
  const float* w1 = (const float*)d_in[1];
  const float* b1 = (const float*)d_in[2];
  const float* w2 = (const float*)d_in[3];
  const float* b2 = (const float*)d_in[4];
  float* out = (float*)d_out;

  char* ws = (char*)d_ws;
  bf16* qkvh = (bf16*)(ws + 0);          // [4096][2048]  Q,K hi
  bf16* qkvl = (bf16*)(ws + 16777216);   // [4096][1024]  Q lo
  bf16* Vt   = (bf16*)(ws + 25165824);   // [1024][4096]  V^T hi
  bf16* xh   = (bf16*)(ws + 33554432);   // [4096][1024]
  bf16* xl   = (bf16*)(ws + 41943040);
  bf16* w1h  = (bf16*)(ws + 50331648);   // [3072][1024]
  bf16* w1l  = (bf16*)(ws + 56623104);
  bf16* w2h  = (bf16*)(ws + 62914560);   // [1024][1024]
  bf16* w2l  = (bf16*)(ws + 65011712);
  bf16* Omh  = xh;                       // reuse (x split dead after V^T gemm)
  bf16* Oml  = xl;

  cvt_all<<<dim3(4096), 256, 0, stream>>>(x, w1, w2, xh, xl, w1h, w1l, w2h, w2l);

  // Q,K = x @ w1[0:2048]^T + b1[0:2048]  -> hi (ld 2048) + lo (Q cols only)
  gemm_split<<<dim3(QKLD / 128, MTOT / 128), 256, 0, stream>>>(
      xh, xl, w1h, w1l, b1, DMODEL, QKLD, nullptr, qkvh, qkvl, QLLD, 0);

  // V^T = w1[2048:3072] @ x^T + b1[2048:] (per-row bias) -> hi only
  gemm_split<<<dim3(MTOT / 128, DMODEL / 128), 256, 0, stream>>>(
      w1h + 2048 * 1024, w1l + 2048 * 1024, xh, xl, b1 + 2048,
      DMODEL, MTOT, nullptr, Vt, nullptr, 0, 1);

  attn_mfma<<<dim3(512), 256, 0, stream>>>(qkvh, qkvl, Vt, Omh, Oml);

  // out = Om @ w2^T + b2 (fp32)
  gemm_split<<<dim3(DMODEL / 128, MTOT / 128), 256, 0, stream>>>(
      Omh, Oml, w2h, w2l, b2, DMODEL, DMODEL, out, nullptr, nullptr, 0, 0);
}

// Round 6
// 319.950 us; speedup vs baseline: 1.1335x; 1.0582x over previous
//
#include <hip/hip_runtime.h>
#include <cstddef>

#define BATCH   2
#define SEQ     2048
#define DMODEL  1024
#define NH      16
#define HDIM    64
#define WIN     256
#define MTOT    4096

typedef __bf16 bf16;
typedef __attribute__((ext_vector_type(8)))  __bf16 bf16x8;
typedef __attribute__((ext_vector_type(4)))  float  f32x4;
typedef __attribute__((ext_vector_type(16))) float  f32x16;

#define GLOAD_LDS(gp, lp) __builtin_amdgcn_global_load_lds( \
    (const __attribute__((address_space(1))) void*)(gp),    \
    (__attribute__((address_space(3))) void*)(lp), 16, 0, 0)

__device__ __forceinline__ float fast_exp2(float x) {
#if __has_builtin(__builtin_amdgcn_exp2f)
  return __builtin_amdgcn_exp2f(x);
#else
  float r; asm("v_exp_f32 %0, %1" : "=v"(r) : "v"(x)); return r;
#endif
}

// ---------------------------------------------------------------------------
// Merged pre-pass: split x, w1, w2 into bf16 hi/lo in one launch.
// ---------------------------------------------------------------------------
__global__ __launch_bounds__(256)
void cvt_all(const float* __restrict__ x, const float* __restrict__ w1,
             const float* __restrict__ w2, bf16* __restrict__ xh,
             bf16* __restrict__ xl, bf16* __restrict__ w1h,
             bf16* __restrict__ w1l, bf16* __restrict__ w2h,
             bf16* __restrict__ w2l) {
  const int bid = blockIdx.x;
  const float* s; bf16 *hp, *lp; int base;
  if (bid < 2048)      { s = x;  hp = xh;  lp = xl;  base = bid * 2048; }
  else if (bid < 3584) { s = w1; hp = w1h; lp = w1l; base = (bid - 2048) * 2048; }
  else                 { s = w2; hp = w2h; lp = w2l; base = (bid - 3584) * 2048; }
  const int i = base + threadIdx.x * 8;
  float4 a = *(const float4*)(s + i);
  float4 c = *(const float4*)(s + i + 4);
  const float f[8] = {a.x, a.y, a.z, a.w, c.x, c.y, c.z, c.w};
  bf16x8 vh, vl;
#pragma unroll
  for (int j = 0; j < 8; ++j) {
    bf16 hh = (bf16)f[j];
    vh[j] = hh;
    vl[j] = (bf16)(f[j] - (float)hh);
  }
  *(bf16x8*)(hp + i) = vh;
  *(bf16x8*)(lp + i) = vl;
}

// ---------------------------------------------------------------------------
// Split-bf16 MFMA GEMM, m97 structure. C = (Ah+Al)(Bh+Bl)^T + bias.
// mode 0: Cf[grow*N+col] = v (fp32, col bias)           -- out-proj
// mode 1: col<1024 -> Qh/Ql row-major ld 1024 (hi+lo);  -- qk-proj
//         col>=1024 -> Ktile frag-order (hi only), col bias
// mode 2: Vtile frag-order (hi only), ROW bias          -- v-proj (B=x)
// Frag-order tile layout, 8KB per (b,h,kt):
//   tile base ((b*16+h)*32+kt)*4096
//   K element (key,d): ((key>>5)*4+(d>>4))*512 + (((d>>3)&1)*32+(key&31))*8 + (d&7)
//   V element (key,d): ((d>>5)*4+((key&63)>>4))*512 + (((key>>3)&1)*32+(d&31))*8 + (key&7)
// ---------------------------------------------------------------------------
__global__ __launch_bounds__(256)
void gemm_split(const bf16* __restrict__ Ah, const bf16* __restrict__ Al,
                const bf16* __restrict__ Bh, const bf16* __restrict__ Bl,
                const float* __restrict__ bias, int K, int N, int mode,
                float* __restrict__ Cf, bf16* __restrict__ P0,
                bf16* __restrict__ P1, bf16* __restrict__ PT) {
  __shared__ bf16 sAh[128 * 32];
  __shared__ bf16 sAl[128 * 32];
  __shared__ bf16 sBh[128 * 32];
  __shared__ bf16 sBl[128 * 32];

  const int t = threadIdx.x, w = t >> 6, lane = t & 63;
  const int ln15 = lane & 15, quad = lane >> 4;
  const int bm = blockIdx.y * 128, bn = blockIdx.x * 128;
  const int wrow = (w & 1) * 64, wcol = (w >> 1) * 64;
  const int drow = lane >> 2;
  const int dkcol = (lane & 3) * 8;

  f32x4 acc[4][4];
#pragma unroll
  for (int i = 0; i < 4; ++i)
#pragma unroll
    for (int j = 0; j < 4; ++j)
#pragma unroll
      for (int r = 0; r < 4; ++r) acc[i][j][r] = 0.f;

  for (int k0 = 0; k0 < K; k0 += 32) {
    __syncthreads();
#pragma unroll
    for (int half = 0; half < 2; ++half) {
      const int r = w * 32 + half * 16 + drow;
      const size_t goffA = (size_t)(bm + r) * K + k0 + dkcol;
      const size_t goffB = (size_t)(bn + r) * K + k0 + dkcol;
      const int loff = (w * 32 + half * 16) * 32;
      GLOAD_LDS(Ah + goffA, sAh + loff);
      GLOAD_LDS(Al + goffA, sAl + loff);
      GLOAD_LDS(Bh + goffB, sBh + loff);
      GLOAD_LDS(Bl + goffB, sBl + loff);
    }
    __syncthreads();

    bf16x8 afh[4], afl[4], bfh[4], bfl[4];
#pragma unroll
    for (int mt = 0; mt < 4; ++mt) {
      const int off = (wrow + mt * 16 + ln15) * 32 + quad * 8;
      afh[mt] = *(const bf16x8*)&sAh[off];
      afl[mt] = *(const bf16x8*)&sAl[off];
    }
#pragma unroll
    for (int nt = 0; nt < 4; ++nt) {
      const int off = (wcol + nt * 16 + ln15) * 32 + quad * 8;
      bfh[nt] = *(const bf16x8*)&sBh[off];
      bfl[nt] = *(const bf16x8*)&sBl[off];
    }
#pragma unroll
    for (int mt = 0; mt < 4; ++mt)
#pragma unroll
      for (int nt = 0; nt < 4; ++nt) {
        acc[mt][nt] = __builtin_amdgcn_mfma_f32_16x16x32_bf16(afh[mt], bfh[nt], acc[mt][nt], 0, 0, 0);
        acc[mt][nt] = __builtin_amdgcn_mfma_f32_16x16x32_bf16(afh[mt], bfl[nt], acc[mt][nt], 0, 0, 0);
        acc[mt][nt] = __builtin_amdgcn_mfma_f32_16x16x32_bf16(afl[mt], bfh[nt], acc[mt][nt], 0, 0, 0);
      }
  }

  float bbcol[4];
#pragma unroll
  for (int nt = 0; nt < 4; ++nt) bbcol[nt] = (mode == 2) ? 0.f : bias[bn + wcol + nt * 16 + ln15];

#pragma unroll
  for (int mt = 0; mt < 4; ++mt)
#pragma unroll
    for (int r = 0; r < 4; ++r) {
      const size_t grow = (size_t)(bm + wrow + mt * 16 + quad * 4 + r);
      const float brow = (mode == 2) ? bias[grow] : 0.f;
#pragma unroll
      for (int nt = 0; nt < 4; ++nt) {
        const int col = bn + wcol + nt * 16 + ln15;
        const float v = acc[mt][nt][r] + bbcol[nt] + brow;
        if (mode == 0) {
          Cf[grow * N + col] = v;
        } else if (mode == 1) {
          if (col < 1024) {
            const bf16 hh = (bf16)v;
            P0[grow * 1024 + col] = hh;
            P1[grow * 1024 + col] = (bf16)(v - (float)hh);
          } else {
            const int btok = (int)(grow >> 11), key = (int)(grow & 2047);
            const int kt = key >> 6, kw = key & 63;
            const int hh2 = (col - 1024) >> 6, d = col & 63;
            const size_t addr = ((size_t)((btok * 16 + hh2) * 32 + kt) << 12)
                              + (((kw >> 5) * 4 + (d >> 4)) << 9)
                              + ((((d >> 3) & 1) << 5) + (kw & 31)) * 8 + (d & 7);
            PT[addr] = (bf16)v;
          }
        } else {
          const int hh2 = (int)(grow >> 6), d = (int)(grow & 63);
          const int btok = col >> 11, key = col & 2047;
          const int kt = key >> 6, kw = key & 63;
          const size_t addr = ((size_t)((btok * 16 + hh2) * 32 + kt) << 12)
                            + (((d >> 5) * 4 + (kw >> 4)) << 9)
                            + ((((kw >> 3) & 1) << 5) + (d & 31)) * 8 + (kw & 7);
          PT[addr] = (bf16)v;
        }
      }
    }
}

// ---------------------------------------------------------------------------
// MFMA flash attention, register-direct, barrier-free, frag-order K/V tiles.
// Block = (b,h) x 128-query tile; 4 independent waves x 32 q-rows; 64-key
// tiles. K/V fragment loads are lane-contiguous 1KB global_load_dwordx4
// (slot*512 + lane*8) from the pre-tiled buffers -- 8 lines/inst, L1-shared
// across the 4 waves. K double-buffered; V issued at iter top. Softmax:
// p = v_exp_f32(s) with scale log2e/8 folded into Q; mask -> p=0 after exp.
// P round-trips via wave-private LDS rows. Row-sum l via ones-column MFMA.
// Complementary-pair swizzle balances the causal tail.
// ---------------------------------------------------------------------------
__global__ __launch_bounds__(256)
void attn_mfma(const bf16* __restrict__ Qh, const bf16* __restrict__ Ql,
               const bf16* __restrict__ Kt, const bf16* __restrict__ Vt,
               bf16* __restrict__ Omh, bf16* __restrict__ Oml) {
  const int t = threadIdx.x, w = t >> 6, lane = t & 63;
  const int ln31 = lane & 31, half = lane >> 5;
  const int bid = blockIdx.x;
  const int p = bid >> 8, r0 = bid & 255;
  const int bh = (r0 >> 4) + (p << 4);
  const int qt = p ? (15 - (r0 & 15)) : (r0 & 15);
  const int i0 = qt * 128;
  const int b = bh >> 4, h = bh & 15;
  const int i0w = i0 + w * 32;                 // this wave's first q row
  const int lim = i0w + WIN;                   // allowed: j <= lim + rl

  __shared__ bf16 sP[128 * 72];                // wave-private rows

  // ---- Q fragments: hi+lo combined, scaled by log2(e)/8, re-split ----
  bf16x8 qh[4], ql[4];
  {
    const size_t rowQ = (size_t)(b * SEQ + i0w + ln31);
#pragma unroll
    for (int ks = 0; ks < 4; ++ks) {
      bf16x8 vh = *(const bf16x8*)(Qh + rowQ * 1024 + h * 64 + ks * 16 + half * 8);
      bf16x8 vl = *(const bf16x8*)(Ql + rowQ * 1024 + h * 64 + ks * 16 + half * 8);
#pragma unroll
      for (int j = 0; j < 8; ++j) {
        float f = ((float)vh[j] + (float)vl[j]) * 0.1803368801111204f;  // log2(e)/8
        bf16 hh = (bf16)f;
        qh[ks][j] = hh;
        ql[ks][j] = (bf16)(f - (float)hh);
      }
    }
  }
  bf16x8 onesf;
#pragma unroll
  for (int j = 0; j < 8; ++j) onesf[j] = (ln31 == 0) ? (bf16)1.0f : (bf16)0.0f;

  f32x16 accO0, accO1, accL;
#pragma unroll
  for (int r = 0; r < 16; ++r) { accO0[r] = 0.f; accO1[r] = 0.f; accL[r] = 0.f; }

  // per-(b,h) tile bases; each tile is 4096 els, frag-slot ordered
  const bf16* KtBH = Kt + ((size_t)(b * 16 + h) << 17);
  const bf16* VtBH = Vt + ((size_t)(b * 16 + h) << 17);
  const int lane8 = lane * 8;

  const int nkt = min((i0w + 31 + WIN) / 64 + 1, SEQ / 64);   // per-wave tiles

  auto loadK = [&](int kt, bf16x8 (&K)[8]) {
    const bf16* tp = KtBH + ((size_t)kt << 12) + lane8;
#pragma unroll
    for (int s = 0; s < 8; ++s)
      K[s] = *(const bf16x8*)(tp + (s << 9));
  };

  auto iter = [&](int kt, bf16x8 (&Kc)[8], bf16x8 (&Kn)[8]) {
    const int j0 = kt * 64;
    // ---- issue V loads (consumed after softmax) ----
    bf16x8 V[8];
    {
      const bf16* tp = VtBH + ((size_t)kt << 12) + lane8;
#pragma unroll
      for (int s = 0; s < 8; ++s)
        V[s] = *(const bf16x8*)(tp + (s << 9));
    }

    // ---- S = Q K^T (Q split: hh + lh) ----
    f32x16 S0, S1;
#pragma unroll
    for (int r = 0; r < 16; ++r) { S0[r] = 0.f; S1[r] = 0.f; }
#pragma unroll
    for (int ks = 0; ks < 4; ++ks) {
      S0 = __builtin_amdgcn_mfma_f32_32x32x16_bf16(qh[ks], Kc[ks],     S0, 0, 0, 0);
      S0 = __builtin_amdgcn_mfma_f32_32x32x16_bf16(ql[ks], Kc[ks],     S0, 0, 0, 0);
      S1 = __builtin_amdgcn_mfma_f32_32x32x16_bf16(qh[ks], Kc[4 + ks], S1, 0, 0, 0);
      S1 = __builtin_amdgcn_mfma_f32_32x32x16_bf16(ql[ks], Kc[4 + ks], S1, 0, 0, 0);
    }

    // ---- prefetch next K tile (covered by softmax + PV) ----
    if (kt + 1 < nkt) loadK(kt + 1, Kn);

    // ---- softmax: p = exp2(s); mask -> 0 after exp; write P to LDS ----
#pragma unroll
    for (int c = 0; c < 2; ++c) {
      f32x16& S = c ? S1 : S0;
      const int vj = j0 + c * 32 + ln31 - lim;        // mask if vj > rl
      const bool may = (j0 + c * 32 + 31) > lim;
#pragma unroll
      for (int r = 0; r < 16; ++r) {
        const int rl = (r & 3) + 8 * (r >> 2) + 4 * half;
        float pv = fast_exp2(S[r]);
        if (may && (vj > rl)) pv = 0.f;
        sP[(w * 32 + rl) * 72 + c * 32 + ln31] = (bf16)pv;
      }
    }

    // ---- O += P V ; l += P 1  (wave-private P rows) ----
#pragma unroll
    for (int ks = 0; ks < 4; ++ks) {
      bf16x8 pA = *(const bf16x8*)&sP[(w * 32 + ln31) * 72 + ks * 16 + half * 8];
      accO0 = __builtin_amdgcn_mfma_f32_32x32x16_bf16(pA, V[ks],     accO0, 0, 0, 0);
      accO1 = __builtin_amdgcn_mfma_f32_32x32x16_bf16(pA, V[4 + ks], accO1, 0, 0, 0);
      accL  = __builtin_amdgcn_mfma_f32_32x32x16_bf16(pA, onesf,     accL,  0, 0, 0);
    }
  };

  bf16x8 KA[8], KB[8];
  loadK(0, KA);
  for (int kt = 0; kt < nkt; kt += 2) {
    iter(kt, KA, KB);
    if (kt + 1 < nkt) iter(kt + 1, KB, KA);
  }

  // ---- epilogue: O /= l, write Om hi/lo ----
#pragma unroll
  for (int r = 0; r < 16; ++r) {
    const int rl = (r & 3) + 8 * (r >> 2) + 4 * half;
    const float lv = __shfl(accL[r], lane & 32, 64);
    const float inv = 1.0f / lv;
    const size_t grow = (size_t)(b * SEQ + i0w + rl);
    const int col0 = h * 64 + ln31;
    const float v0 = accO0[r] * inv;
    const float v1 = accO1[r] * inv;
    const bf16 h0 = (bf16)v0, h1 = (bf16)v1;
    Omh[grow * DMODEL + col0]      = h0;
    Oml[grow * DMODEL + col0]      = (bf16)(v0 - (float)h0);
    Omh[grow * DMODEL + col0 + 32] = h1;
    Oml[grow * DMODEL + col0 + 32] = (bf16)(v1 - (float)h1);
  }
}

// ---------------------------------------------------------------------------
extern "C" void kernel_launch(void* const* d_in, const int* in_sizes, int n_in,
                              void* d_out, int out_size, void* d_ws, size_t ws_size,
                              hipStream_t stream) {
  const float* x  = (const float*)d_in[0];
  const float* w1 = (const float*)d_in[1];
  const float* b1 = (const float*)d_in[2];
  const float* w2 = (const float*)d_in[3];
  const float* b2 = (const float*)d_in[4];
  float* out = (float*)d_out;

  char* ws = (char*)d_ws;
  bf16* Qh   = (bf16*)(ws + 0);          // [4096][1024]
  bf16* Ql   = (bf16*)(ws + 8388608);    // [4096][1024]
  bf16* Kt   = (bf16*)(ws + 16777216);   // frag-order tiles, 8 MB
  bf16* Vt   = (bf16*)(ws + 25165824);   // frag-order tiles, 8 MB
  bf16* xh   = (bf16*)(ws + 33554432);   // [4096][1024]
  bf16* xl   = (bf16*)(ws + 41943040);
  bf16* w1h  = (bf16*)(ws + 50331648);   // [3072][1024]
  bf16* w1l  = (bf16*)(ws + 56623104);
  bf16* w2h  = (bf16*)(ws + 62914560);   // [1024][1024]
  bf16* w2l  = (bf16*)(ws + 65011712);
  bf16* Omh  = xh;                       // reuse (x dead after V^T gemm)
  bf16* Oml  = xl;

  cvt_all<<<dim3(4096), 256, 0, stream>>>(x, w1, w2, xh, xl, w1h, w1l, w2h, w2l);

  // Q (hi+lo row-major) and K (frag tiles): x @ w1[0:2048]^T + b1[0:2048]
  gemm_split<<<dim3(2048 / 128, MTOT / 128), 256, 0, stream>>>(
      xh, xl, w1h, w1l, b1, DMODEL, 2048, 1, nullptr, Qh, Ql, Kt);

  // V^T frag tiles: w1[2048:3072] @ x^T + b1[2048:] (row bias)
  gemm_split<<<dim3(MTOT / 128, DMODEL / 128), 256, 0, stream>>>(
      w1h + 2048 * 1024, w1l + 2048 * 1024, xh, xl, b1 + 2048,
      DMODEL, MTOT, 2, nullptr, nullptr, nullptr, Vt);

  attn_mfma<<<dim3(512), 256, 0, stream>>>(Qh, Ql, Kt, Vt, Omh, Oml);

  // out = Om @ w2^T + b2 (fp32)
  gemm_split<<<dim3(DMODEL / 128, MTOT / 128), 256, 0, stream>>>(
      Omh, Oml, w2h, w2l, b2, DMODEL, DMODEL, 0, out, nullptr, nullptr, nullptr);
}

// Round 7
// 296.762 us; speedup vs baseline: 1.2221x; 1.0781x over previous
//
#include <hip/hip_runtime.h>
#include <cstddef>

#define BATCH   2
#define SEQ     2048
#define DMODEL  1024
#define NH      16
#define HDIM    64
#define WIN     256
#define MTOT    4096

typedef __bf16 bf16;
typedef __attribute__((ext_vector_type(8)))  __bf16 bf16x8;
typedef __attribute__((ext_vector_type(4)))  float  f32x4;
typedef __attribute__((ext_vector_type(16))) float  f32x16;

#define GLOAD_LDS(gp, lp) __builtin_amdgcn_global_load_lds( \
    (const __attribute__((address_space(1))) void*)(gp),    \
    (__attribute__((address_space(3))) void*)(lp), 16, 0, 0)

__device__ __forceinline__ float fast_exp2(float x) {
#if __has_builtin(__builtin_amdgcn_exp2f)
  return __builtin_amdgcn_exp2f(x);
#else
  float r; asm("v_exp_f32 %0, %1" : "=v"(r) : "v"(x)); return r;
#endif
}

// ---------------------------------------------------------------------------
// Merged pre-pass: split x, w1, w2 into bf16 hi/lo in one launch.
// ---------------------------------------------------------------------------
__global__ __launch_bounds__(256)
void cvt_all(const float* __restrict__ x, const float* __restrict__ w1,
             const float* __restrict__ w2, bf16* __restrict__ xh,
             bf16* __restrict__ xl, bf16* __restrict__ w1h,
             bf16* __restrict__ w1l, bf16* __restrict__ w2h,
             bf16* __restrict__ w2l) {
  const int bid = blockIdx.x;
  const float* s; bf16 *hp, *lp; int base;
  if (bid < 2048)      { s = x;  hp = xh;  lp = xl;  base = bid * 2048; }
  else if (bid < 3584) { s = w1; hp = w1h; lp = w1l; base = (bid - 2048) * 2048; }
  else                 { s = w2; hp = w2h; lp = w2l; base = (bid - 3584) * 2048; }
  const int i = base + threadIdx.x * 8;
  float4 a = *(const float4*)(s + i);
  float4 c = *(const float4*)(s + i + 4);
  const float f[8] = {a.x, a.y, a.z, a.w, c.x, c.y, c.z, c.w};
  bf16x8 vh, vl;
#pragma unroll
  for (int j = 0; j < 8; ++j) {
    bf16 hh = (bf16)f[j];
    vh[j] = hh;
    vl[j] = (bf16)(f[j] - (float)hh);
  }
  *(bf16x8*)(hp + i) = vh;
  *(bf16x8*)(lp + i) = vl;
}

// ---------------------------------------------------------------------------
// Split-bf16 MFMA GEMM, m97 structure. C = (Ah+Al)(Bh+Bl)^T + bias.
// mode 0: Cf[grow*N+col] = v (fp32, col bias)           -- out-proj
// mode 1: col<1024 -> Qh/Ql row-major ld 1024 (hi+lo), 3 MFMA;
//         col>=1024 -> Ktile frag-order (hi only), 1 MFMA (hh) -- K output
//         is bf16 anyway: hh-only product err ~ sqrt2 x output rounding.
// Frag-order K tile layout, 8KB per (b,h,kt): base ((b*16+h)*32+kt)*4096,
//   elem (key,d): ((key>>5)*4+(d>>4))*512 + (((d>>3)&1)*32+(key&31))*8 + (d&7)
// ---------------------------------------------------------------------------
__global__ __launch_bounds__(256)
void gemm_split(const bf16* __restrict__ Ah, const bf16* __restrict__ Al,
                const bf16* __restrict__ Bh, const bf16* __restrict__ Bl,
                const float* __restrict__ bias, int K, int N, int mode,
                float* __restrict__ Cf, bf16* __restrict__ P0,
                bf16* __restrict__ P1, bf16* __restrict__ PT) {
  __shared__ bf16 sAh[128 * 32];
  __shared__ bf16 sAl[128 * 32];
  __shared__ bf16 sBh[128 * 32];
  __shared__ bf16 sBl[128 * 32];

  const int t = threadIdx.x, w = t >> 6, lane = t & 63;
  const int ln15 = lane & 15, quad = lane >> 4;
  const int bm = blockIdx.y * 128, bn = blockIdx.x * 128;
  const int wrow = (w & 1) * 64, wcol = (w >> 1) * 64;
  const int drow = lane >> 2;
  const int dkcol = (lane & 3) * 8;
  const bool cross = !(mode == 1 && bn >= 1024);   // wave-uniform

  f32x4 acc[4][4];
#pragma unroll
  for (int i = 0; i < 4; ++i)
#pragma unroll
    for (int j = 0; j < 4; ++j)
#pragma unroll
      for (int r = 0; r < 4; ++r) acc[i][j][r] = 0.f;

  for (int k0 = 0; k0 < K; k0 += 32) {
    __syncthreads();
#pragma unroll
    for (int half = 0; half < 2; ++half) {
      const int r = w * 32 + half * 16 + drow;
      const size_t goffA = (size_t)(bm + r) * K + k0 + dkcol;
      const size_t goffB = (size_t)(bn + r) * K + k0 + dkcol;
      const int loff = (w * 32 + half * 16) * 32;
      GLOAD_LDS(Ah + goffA, sAh + loff);
      GLOAD_LDS(Bh + goffB, sBh + loff);
      if (cross) {
        GLOAD_LDS(Al + goffA, sAl + loff);
        GLOAD_LDS(Bl + goffB, sBl + loff);
      }
    }
    __syncthreads();

    bf16x8 afh[4], afl[4], bfh[4], bfl[4];
#pragma unroll
    for (int mt = 0; mt < 4; ++mt) {
      const int off = (wrow + mt * 16 + ln15) * 32 + quad * 8;
      afh[mt] = *(const bf16x8*)&sAh[off];
      if (cross) afl[mt] = *(const bf16x8*)&sAl[off];
    }
#pragma unroll
    for (int nt = 0; nt < 4; ++nt) {
      const int off = (wcol + nt * 16 + ln15) * 32 + quad * 8;
      bfh[nt] = *(const bf16x8*)&sBh[off];
      if (cross) bfl[nt] = *(const bf16x8*)&sBl[off];
    }
#pragma unroll
    for (int mt = 0; mt < 4; ++mt)
#pragma unroll
      for (int nt = 0; nt < 4; ++nt) {
        acc[mt][nt] = __builtin_amdgcn_mfma_f32_16x16x32_bf16(afh[mt], bfh[nt], acc[mt][nt], 0, 0, 0);
        if (cross) {
          acc[mt][nt] = __builtin_amdgcn_mfma_f32_16x16x32_bf16(afh[mt], bfl[nt], acc[mt][nt], 0, 0, 0);
          acc[mt][nt] = __builtin_amdgcn_mfma_f32_16x16x32_bf16(afl[mt], bfh[nt], acc[mt][nt], 0, 0, 0);
        }
      }
  }

  float bbcol[4];
#pragma unroll
  for (int nt = 0; nt < 4; ++nt) bbcol[nt] = bias[bn + wcol + nt * 16 + ln15];

#pragma unroll
  for (int mt = 0; mt < 4; ++mt)
#pragma unroll
    for (int r = 0; r < 4; ++r) {
      const size_t grow = (size_t)(bm + wrow + mt * 16 + quad * 4 + r);
#pragma unroll
      for (int nt = 0; nt < 4; ++nt) {
        const int col = bn + wcol + nt * 16 + ln15;
        const float v = acc[mt][nt][r] + bbcol[nt];
        if (mode == 0) {
          Cf[grow * N + col] = v;
        } else {
          if (col < 1024) {
            const bf16 hh = (bf16)v;
            P0[grow * 1024 + col] = hh;
            P1[grow * 1024 + col] = (bf16)(v - (float)hh);
          } else {
            const int btok = (int)(grow >> 11), key = (int)(grow & 2047);
            const int kt = key >> 6, kw = key & 63;
            const int hh2 = (col - 1024) >> 6, d = col & 63;
            const size_t addr = ((size_t)((btok * 16 + hh2) * 32 + kt) << 12)
                              + (((kw >> 5) * 4 + (d >> 4)) << 9)
                              + ((((d >> 3) & 1) << 5) + (kw & 31)) * 8 + (d & 7);
            PT[addr] = (bf16)v;
          }
        }
      }
    }
}

// ---------------------------------------------------------------------------
// hh-only GEMM for V^T: C = Ah·Bh^T + bias[row], output V frag-order tiles.
// 2 LDS buffers, 1 MFMA per tile step -- V is bf16 hi-only, so the hh-only
// product error is on par with its output rounding.
// V tile elem (key,d): ((d>>5)*4+((key&63)>>4))*512
//                      + (((key>>3)&1)*32+(d&31))*8 + (key&7)
// ---------------------------------------------------------------------------
__global__ __launch_bounds__(256)
void gemm_hh_v(const bf16* __restrict__ Ah, const bf16* __restrict__ Bh,
               const float* __restrict__ bias, int K, int N,
               bf16* __restrict__ PT) {
  __shared__ bf16 sAh[128 * 32];
  __shared__ bf16 sBh[128 * 32];

  const int t = threadIdx.x, w = t >> 6, lane = t & 63;
  const int ln15 = lane & 15, quad = lane >> 4;
  const int bm = blockIdx.y * 128, bn = blockIdx.x * 128;
  const int wrow = (w & 1) * 64, wcol = (w >> 1) * 64;
  const int drow = lane >> 2;
  const int dkcol = (lane & 3) * 8;

  f32x4 acc[4][4];
#pragma unroll
  for (int i = 0; i < 4; ++i)
#pragma unroll
    for (int j = 0; j < 4; ++j)
#pragma unroll
      for (int r = 0; r < 4; ++r) acc[i][j][r] = 0.f;

  for (int k0 = 0; k0 < K; k0 += 32) {
    __syncthreads();
#pragma unroll
    for (int half = 0; half < 2; ++half) {
      const int r = w * 32 + half * 16 + drow;
      const int loff = (w * 32 + half * 16) * 32;
      GLOAD_LDS(Ah + (size_t)(bm + r) * K + k0 + dkcol, sAh + loff);
      GLOAD_LDS(Bh + (size_t)(bn + r) * K + k0 + dkcol, sBh + loff);
    }
    __syncthreads();

    bf16x8 af[4], bf[4];
#pragma unroll
    for (int mt = 0; mt < 4; ++mt)
      af[mt] = *(const bf16x8*)&sAh[(wrow + mt * 16 + ln15) * 32 + quad * 8];
#pragma unroll
    for (int nt = 0; nt < 4; ++nt)
      bf[nt] = *(const bf16x8*)&sBh[(wcol + nt * 16 + ln15) * 32 + quad * 8];
#pragma unroll
    for (int mt = 0; mt < 4; ++mt)
#pragma unroll
      for (int nt = 0; nt < 4; ++nt)
        acc[mt][nt] = __builtin_amdgcn_mfma_f32_16x16x32_bf16(af[mt], bf[nt], acc[mt][nt], 0, 0, 0);
  }

#pragma unroll
  for (int mt = 0; mt < 4; ++mt)
#pragma unroll
    for (int r = 0; r < 4; ++r) {
      const size_t grow = (size_t)(bm + wrow + mt * 16 + quad * 4 + r);
      const float brow = bias[grow];
      const int hh2 = (int)(grow >> 6), d = (int)(grow & 63);
#pragma unroll
      for (int nt = 0; nt < 4; ++nt) {
        const int col = bn + wcol + nt * 16 + ln15;
        const float v = acc[mt][nt][r] + brow;
        const int btok = col >> 11, key = col & 2047;
        const int kt = key >> 6, kw = key & 63;
        const size_t addr = ((size_t)((btok * 16 + hh2) * 32 + kt) << 12)
                          + (((d >> 5) * 4 + (kw >> 4)) << 9)
                          + ((((kw >> 3) & 1) << 5) + (d & 31)) * 8 + (kw & 7);
        PT[addr] = (bf16)v;
      }
    }
}

// ---------------------------------------------------------------------------
// MFMA flash attention, register-direct, barrier-free, frag-order K/V tiles.
// XCD-locality swizzle: all 16 q-blocks of one (b,h) share bid%8 -> same XCD
// under round-robin dispatch, so K/V/Q (~0.75MB per bh; 4 bh = 3MB) stay
// resident in that XCD's 4MB L2 -- kills the 3-4x HBM re-fetch seen in R6.
// qt remapped so co-resident pairs (bid, bid+256) remain complementary.
// ---------------------------------------------------------------------------
__global__ __launch_bounds__(256)
void attn_mfma(const bf16* __restrict__ Qh, const bf16* __restrict__ Ql,
               const bf16* __restrict__ Kt, const bf16* __restrict__ Vt,
               bf16* __restrict__ Omh, bf16* __restrict__ Oml) {
  const int t = threadIdx.x, w = t >> 6, lane = t & 63;
  const int ln31 = lane & 31, half = lane >> 5;
  const int bid = blockIdx.x;
  const int bh = ((bid >> 3) & 3) * 8 + (bid & 7);   // bid%8 == bh%8 -> XCD
  const int qi = bid >> 5;                           // 0..15
  const int qt = (qi < 8) ? qi : 23 - qi;            // complementary pairing
  const int i0 = qt * 128;
  const int b = bh >> 4, h = bh & 15;
  const int i0w = i0 + w * 32;                 // this wave's first q row
  const int lim = i0w + WIN;                   // allowed: j <= lim + rl

  __shared__ bf16 sP[128 * 72];                // wave-private rows

  // ---- Q fragments: hi+lo combined, scaled by log2(e)/8, re-split ----
  bf16x8 qh[4], ql[4];
  {
    const size_t rowQ = (size_t)(b * SEQ + i0w + ln31);
#pragma unroll
    for (int ks = 0; ks < 4; ++ks) {
      bf16x8 vh = *(const bf16x8*)(Qh + rowQ * 1024 + h * 64 + ks * 16 + half * 8);
      bf16x8 vl = *(const bf16x8*)(Ql + rowQ * 1024 + h * 64 + ks * 16 + half * 8);
#pragma unroll
      for (int j = 0; j < 8; ++j) {
        float f = ((float)vh[j] + (float)vl[j]) * 0.1803368801111204f;  // log2(e)/8
        bf16 hh = (bf16)f;
        qh[ks][j] = hh;
        ql[ks][j] = (bf16)(f - (float)hh);
      }
    }
  }
  bf16x8 onesf;
#pragma unroll
  for (int j = 0; j < 8; ++j) onesf[j] = (ln31 == 0) ? (bf16)1.0f : (bf16)0.0f;

  f32x16 accO0, accO1, accL;
#pragma unroll
  for (int r = 0; r < 16; ++r) { accO0[r] = 0.f; accO1[r] = 0.f; accL[r] = 0.f; }

  // per-(b,h) tile bases; each tile is 4096 els, frag-slot ordered
  const bf16* KtBH = Kt + ((size_t)(b * 16 + h) << 17);
  const bf16* VtBH = Vt + ((size_t)(b * 16 + h) << 17);
  const int lane8 = lane * 8;

  const int nkt = min((i0w + 31 + WIN) / 64 + 1, SEQ / 64);   // per-wave tiles

  auto loadK = [&](int kt, bf16x8 (&K)[8]) {
    const bf16* tp = KtBH + ((size_t)kt << 12) + lane8;
#pragma unroll
    for (int s = 0; s < 8; ++s)
      K[s] = *(const bf16x8*)(tp + (s << 9));
  };

  auto iter = [&](int kt, bf16x8 (&Kc)[8], bf16x8 (&Kn)[8]) {
    const int j0 = kt * 64;
    // ---- issue V loads (consumed after softmax) ----
    bf16x8 V[8];
    {
      const bf16* tp = VtBH + ((size_t)kt << 12) + lane8;
#pragma unroll
      for (int s = 0; s < 8; ++s)
        V[s] = *(const bf16x8*)(tp + (s << 9));
    }

    // ---- S = Q K^T (Q split: hh + lh) ----
    f32x16 S0, S1;
#pragma unroll
    for (int r = 0; r < 16; ++r) { S0[r] = 0.f; S1[r] = 0.f; }
#pragma unroll
    for (int ks = 0; ks < 4; ++ks) {
      S0 = __builtin_amdgcn_mfma_f32_32x32x16_bf16(qh[ks], Kc[ks],     S0, 0, 0, 0);
      S0 = __builtin_amdgcn_mfma_f32_32x32x16_bf16(ql[ks], Kc[ks],     S0, 0, 0, 0);
      S1 = __builtin_amdgcn_mfma_f32_32x32x16_bf16(qh[ks], Kc[4 + ks], S1, 0, 0, 0);
      S1 = __builtin_amdgcn_mfma_f32_32x32x16_bf16(ql[ks], Kc[4 + ks], S1, 0, 0, 0);
    }

    // ---- prefetch next K tile (covered by softmax + PV) ----
    if (kt + 1 < nkt) loadK(kt + 1, Kn);

    // ---- softmax: p = exp2(s); mask -> 0 after exp; write P to LDS ----
#pragma unroll
    for (int c = 0; c < 2; ++c) {
      f32x16& S = c ? S1 : S0;
      const int vj = j0 + c * 32 + ln31 - lim;        // mask if vj > rl
      const bool may = (j0 + c * 32 + 31) > lim;
#pragma unroll
      for (int r = 0; r < 16; ++r) {
        const int rl = (r & 3) + 8 * (r >> 2) + 4 * half;
        float pv = fast_exp2(S[r]);
        if (may && (vj > rl)) pv = 0.f;
        sP[(w * 32 + rl) * 72 + c * 32 + ln31] = (bf16)pv;
      }
    }

    // ---- O += P V ; l += P 1  (wave-private P rows) ----
#pragma unroll
    for (int ks = 0; ks < 4; ++ks) {
      bf16x8 pA = *(const bf16x8*)&sP[(w * 32 + ln31) * 72 + ks * 16 + half * 8];
      accO0 = __builtin_amdgcn_mfma_f32_32x32x16_bf16(pA, V[ks],     accO0, 0, 0, 0);
      accO1 = __builtin_amdgcn_mfma_f32_32x32x16_bf16(pA, V[4 + ks], accO1, 0, 0, 0);
      accL  = __builtin_amdgcn_mfma_f32_32x32x16_bf16(pA, onesf,     accL,  0, 0, 0);
    }
  };

  bf16x8 KA[8], KB[8];
  loadK(0, KA);
  for (int kt = 0; kt < nkt; kt += 2) {
    iter(kt, KA, KB);
    if (kt + 1 < nkt) iter(kt + 1, KB, KA);
  }

  // ---- epilogue: O /= l, write Om hi/lo ----
#pragma unroll
  for (int r = 0; r < 16; ++r) {
    const int rl = (r & 3) + 8 * (r >> 2) + 4 * half;
    const float lv = __shfl(accL[r], lane & 32, 64);
    const float inv = 1.0f / lv;
    const size_t grow = (size_t)(b * SEQ + i0w + rl);
    const int col0 = h * 64 + ln31;
    const float v0 = accO0[r] * inv;
    const float v1 = accO1[r] * inv;
    const bf16 h0 = (bf16)v0, h1 = (bf16)v1;
    Omh[grow * DMODEL + col0]      = h0;
    Oml[grow * DMODEL + col0]      = (bf16)(v0 - (float)h0);
    Omh[grow * DMODEL + col0 + 32] = h1;
    Oml[grow * DMODEL + col0 + 32] = (bf16)(v1 - (float)h1);
  }
}

// ---------------------------------------------------------------------------
extern "C" void kernel_launch(void* const* d_in, const int* in_sizes, int n_in,
                              void* d_out, int out_size, void* d_ws, size_t ws_size,
                              hipStream_t stream) {
  const float* x  = (const float*)d_in[0];
  const float* w1 = (const float*)d_in[1];
  const float* b1 = (const float*)d_in[2];
  const float* w2 = (const float*)d_in[3];
  const float* b2 = (const float*)d_in[4];
  float* out = (float*)d_out;

  char* ws = (char*)d_ws;
  bf16* Qh   = (bf16*)(ws + 0);          // [4096][1024]
  bf16* Ql   = (bf16*)(ws + 8388608);    // [4096][1024]
  bf16* Kt   = (bf16*)(ws + 16777216);   // frag-order tiles, 8 MB
  bf16* Vt   = (bf16*)(ws + 25165824);   // frag-order tiles, 8 MB
  bf16* xh   = (bf16*)(ws + 33554432);   // [4096][1024]
  bf16* xl   = (bf16*)(ws + 41943040);
  bf16* w1h  = (bf16*)(ws + 50331648);   // [3072][1024]
  bf16* w1l  = (bf16*)(ws + 56623104);
  bf16* w2h  = (bf16*)(ws + 62914560);   // [1024][1024]
  bf16* w2l  = (bf16*)(ws + 65011712);
  bf16* Omh  = xh;                       // reuse (x dead after V^T gemm)
  bf16* Oml  = xl;

  cvt_all<<<dim3(4096), 256, 0, stream>>>(x, w1, w2, xh, xl, w1h, w1l, w2h, w2l);

  // Q (hi+lo, 3 MFMA) and K (frag tiles, 1 MFMA): x @ w1[0:2048]^T + b1
  gemm_split<<<dim3(2048 / 128, MTOT / 128), 256, 0, stream>>>(
      xh, xl, w1h, w1l, b1, DMODEL, 2048, 1, nullptr, Qh, Ql, Kt);

  // V^T frag tiles: w1[2048:3072] @ x^T + b1[2048:] (row bias), hh-only
  gemm_hh_v<<<dim3(MTOT / 128, DMODEL / 128), 256, 0, stream>>>(
      w1h + 2048 * 1024, xh, b1 + 2048, DMODEL, MTOT, Vt);

  attn_mfma<<<dim3(512), 256, 0, stream>>>(Qh, Ql, Kt, Vt, Omh, Oml);

  // out = Om @ w2^T + b2 (fp32)
  gemm_split<<<dim3(DMODEL / 128, MTOT / 128), 256, 0, stream>>>(
      Omh, Oml, w2h, w2l, b2, DMODEL, DMODEL, 0, out, nullptr, nullptr, nullptr);
}

// Round 8
// 294.302 us; speedup vs baseline: 1.2323x; 1.0084x over previous
//
#include <hip/hip_runtime.h>
#include <cstddef>

#define BATCH   2
#define SEQ     2048
#define DMODEL  1024
#define NH      16
#define HDIM    64
#define WIN     256
#define MTOT    4096

typedef __bf16 bf16;
typedef __attribute__((ext_vector_type(8)))  __bf16 bf16x8;
typedef __attribute__((ext_vector_type(4)))  float  f32x4;
typedef __attribute__((ext_vector_type(16))) float  f32x16;

#define GLOAD_LDS(gp, lp) __builtin_amdgcn_global_load_lds( \
    (const __attribute__((address_space(1))) void*)(gp),    \
    (__attribute__((address_space(3))) void*)(lp), 16, 0, 0)

__device__ __forceinline__ float fast_exp2(float x) {
#if __has_builtin(__builtin_amdgcn_exp2f)
  return __builtin_amdgcn_exp2f(x);
#else
  float r; asm("v_exp_f32 %0, %1" : "=v"(r) : "v"(x)); return r;
#endif
}

// ---------------------------------------------------------------------------
// Merged pre-pass: split x, w1, w2 into bf16 hi/lo in one launch.
// ---------------------------------------------------------------------------
__global__ __launch_bounds__(256)
void cvt_all(const float* __restrict__ x, const float* __restrict__ w1,
             const float* __restrict__ w2, bf16* __restrict__ xh,
             bf16* __restrict__ xl, bf16* __restrict__ w1h,
             bf16* __restrict__ w1l, bf16* __restrict__ w2h,
             bf16* __restrict__ w2l) {
  const int bid = blockIdx.x;
  const float* s; bf16 *hp, *lp; int base;
  if (bid < 2048)      { s = x;  hp = xh;  lp = xl;  base = bid * 2048; }
  else if (bid < 3584) { s = w1; hp = w1h; lp = w1l; base = (bid - 2048) * 2048; }
  else                 { s = w2; hp = w2h; lp = w2l; base = (bid - 3584) * 2048; }
  const int i = base + threadIdx.x * 8;
  float4 a = *(const float4*)(s + i);
  float4 c = *(const float4*)(s + i + 4);
  const float f[8] = {a.x, a.y, a.z, a.w, c.x, c.y, c.z, c.w};
  bf16x8 vh, vl;
#pragma unroll
  for (int j = 0; j < 8; ++j) {
    bf16 hh = (bf16)f[j];
    vh[j] = hh;
    vl[j] = (bf16)(f[j] - (float)hh);
  }
  *(bf16x8*)(hp + i) = vh;
  *(bf16x8*)(lp + i) = vl;
}

// ---------------------------------------------------------------------------
// Split-bf16 MFMA GEMM, m97 structure. C = (Ah+Al)(Bh+Bl)^T + bias.
// mode 0: Cf[grow*N+col] = v (fp32, col bias)           -- out-proj
// mode 1: col<1024 -> Qh/Ql row-major ld 1024 (hi+lo), 3 MFMA;
//         col>=1024 -> Ktile frag-order (hi only), 1 MFMA (hh)
// Frag-order K tile layout, 8KB per (b,h,kt): base ((b*16+h)*32+kt)*4096,
//   elem (key,d): ((key>>5)*4+(d>>4))*512 + (((d>>3)&1)*32+(key&31))*8 + (d&7)
// ---------------------------------------------------------------------------
__global__ __launch_bounds__(256)
void gemm_split(const bf16* __restrict__ Ah, const bf16* __restrict__ Al,
                const bf16* __restrict__ Bh, const bf16* __restrict__ Bl,
                const float* __restrict__ bias, int K, int N, int mode,
                float* __restrict__ Cf, bf16* __restrict__ P0,
                bf16* __restrict__ P1, bf16* __restrict__ PT) {
  __shared__ bf16 sAh[128 * 32];
  __shared__ bf16 sAl[128 * 32];
  __shared__ bf16 sBh[128 * 32];
  __shared__ bf16 sBl[128 * 32];

  const int t = threadIdx.x, w = t >> 6, lane = t & 63;
  const int ln15 = lane & 15, quad = lane >> 4;
  const int bm = blockIdx.y * 128, bn = blockIdx.x * 128;
  const int wrow = (w & 1) * 64, wcol = (w >> 1) * 64;
  const int drow = lane >> 2;
  const int dkcol = (lane & 3) * 8;
  const bool cross = !(mode == 1 && bn >= 1024);   // wave-uniform

  f32x4 acc[4][4];
#pragma unroll
  for (int i = 0; i < 4; ++i)
#pragma unroll
    for (int j = 0; j < 4; ++j)
#pragma unroll
      for (int r = 0; r < 4; ++r) acc[i][j][r] = 0.f;

  for (int k0 = 0; k0 < K; k0 += 32) {
    __syncthreads();
#pragma unroll
    for (int half = 0; half < 2; ++half) {
      const int r = w * 32 + half * 16 + drow;
      const size_t goffA = (size_t)(bm + r) * K + k0 + dkcol;
      const size_t goffB = (size_t)(bn + r) * K + k0 + dkcol;
      const int loff = (w * 32 + half * 16) * 32;
      GLOAD_LDS(Ah + goffA, sAh + loff);
      GLOAD_LDS(Bh + goffB, sBh + loff);
      if (cross) {
        GLOAD_LDS(Al + goffA, sAl + loff);
        GLOAD_LDS(Bl + goffB, sBl + loff);
      }
    }
    __syncthreads();

    bf16x8 afh[4], afl[4], bfh[4], bfl[4];
#pragma unroll
    for (int mt = 0; mt < 4; ++mt) {
      const int off = (wrow + mt * 16 + ln15) * 32 + quad * 8;
      afh[mt] = *(const bf16x8*)&sAh[off];
      if (cross) afl[mt] = *(const bf16x8*)&sAl[off];
    }
#pragma unroll
    for (int nt = 0; nt < 4; ++nt) {
      const int off = (wcol + nt * 16 + ln15) * 32 + quad * 8;
      bfh[nt] = *(const bf16x8*)&sBh[off];
      if (cross) bfl[nt] = *(const bf16x8*)&sBl[off];
    }
#pragma unroll
    for (int mt = 0; mt < 4; ++mt)
#pragma unroll
      for (int nt = 0; nt < 4; ++nt) {
        acc[mt][nt] = __builtin_amdgcn_mfma_f32_16x16x32_bf16(afh[mt], bfh[nt], acc[mt][nt], 0, 0, 0);
        if (cross) {
          acc[mt][nt] = __builtin_amdgcn_mfma_f32_16x16x32_bf16(afh[mt], bfl[nt], acc[mt][nt], 0, 0, 0);
          acc[mt][nt] = __builtin_amdgcn_mfma_f32_16x16x32_bf16(afl[mt], bfh[nt], acc[mt][nt], 0, 0, 0);
        }
      }
  }

  float bbcol[4];
#pragma unroll
  for (int nt = 0; nt < 4; ++nt) bbcol[nt] = bias[bn + wcol + nt * 16 + ln15];

#pragma unroll
  for (int mt = 0; mt < 4; ++mt)
#pragma unroll
    for (int r = 0; r < 4; ++r) {
      const size_t grow = (size_t)(bm + wrow + mt * 16 + quad * 4 + r);
#pragma unroll
      for (int nt = 0; nt < 4; ++nt) {
        const int col = bn + wcol + nt * 16 + ln15;
        const float v = acc[mt][nt][r] + bbcol[nt];
        if (mode == 0) {
          Cf[grow * N + col] = v;
        } else {
          if (col < 1024) {
            const bf16 hh = (bf16)v;
            P0[grow * 1024 + col] = hh;
            P1[grow * 1024 + col] = (bf16)(v - (float)hh);
          } else {
            const int btok = (int)(grow >> 11), key = (int)(grow & 2047);
            const int kt = key >> 6, kw = key & 63;
            const int hh2 = (col - 1024) >> 6, d = col & 63;
            const size_t addr = ((size_t)((btok * 16 + hh2) * 32 + kt) << 12)
                              + (((kw >> 5) * 4 + (d >> 4)) << 9)
                              + ((((d >> 3) & 1) << 5) + (kw & 31)) * 8 + (d & 7);
            PT[addr] = (bf16)v;
          }
        }
      }
    }
}

// ---------------------------------------------------------------------------
// hh-only GEMM for V^T: C = Ah·Bh^T + bias[row], output V frag-order tiles.
// V tile elem (key,d): ((d>>5)*4+((key&63)>>4))*512
//                      + (((key>>3)&1)*32+(d&31))*8 + (key&7)
// ---------------------------------------------------------------------------
__global__ __launch_bounds__(256)
void gemm_hh_v(const bf16* __restrict__ Ah, const bf16* __restrict__ Bh,
               const float* __restrict__ bias, int K, int N,
               bf16* __restrict__ PT) {
  __shared__ bf16 sAh[128 * 32];
  __shared__ bf16 sBh[128 * 32];

  const int t = threadIdx.x, w = t >> 6, lane = t & 63;
  const int ln15 = lane & 15, quad = lane >> 4;
  const int bm = blockIdx.y * 128, bn = blockIdx.x * 128;
  const int wrow = (w & 1) * 64, wcol = (w >> 1) * 64;
  const int drow = lane >> 2;
  const int dkcol = (lane & 3) * 8;

  f32x4 acc[4][4];
#pragma unroll
  for (int i = 0; i < 4; ++i)
#pragma unroll
    for (int j = 0; j < 4; ++j)
#pragma unroll
      for (int r = 0; r < 4; ++r) acc[i][j][r] = 0.f;

  for (int k0 = 0; k0 < K; k0 += 32) {
    __syncthreads();
#pragma unroll
    for (int half = 0; half < 2; ++half) {
      const int r = w * 32 + half * 16 + drow;
      const int loff = (w * 32 + half * 16) * 32;
      GLOAD_LDS(Ah + (size_t)(bm + r) * K + k0 + dkcol, sAh + loff);
      GLOAD_LDS(Bh + (size_t)(bn + r) * K + k0 + dkcol, sBh + loff);
    }
    __syncthreads();

    bf16x8 af[4], bf[4];
#pragma unroll
    for (int mt = 0; mt < 4; ++mt)
      af[mt] = *(const bf16x8*)&sAh[(wrow + mt * 16 + ln15) * 32 + quad * 8];
#pragma unroll
    for (int nt = 0; nt < 4; ++nt)
      bf[nt] = *(const bf16x8*)&sBh[(wcol + nt * 16 + ln15) * 32 + quad * 8];
#pragma unroll
    for (int mt = 0; mt < 4; ++mt)
#pragma unroll
      for (int nt = 0; nt < 4; ++nt)
        acc[mt][nt] = __builtin_amdgcn_mfma_f32_16x16x32_bf16(af[mt], bf[nt], acc[mt][nt], 0, 0, 0);
  }

#pragma unroll
  for (int mt = 0; mt < 4; ++mt)
#pragma unroll
    for (int r = 0; r < 4; ++r) {
      const size_t grow = (size_t)(bm + wrow + mt * 16 + quad * 4 + r);
      const float brow = bias[grow];
      const int hh2 = (int)(grow >> 6), d = (int)(grow & 63);
#pragma unroll
      for (int nt = 0; nt < 4; ++nt) {
        const int col = bn + wcol + nt * 16 + ln15;
        const float v = acc[mt][nt][r] + brow;
        const int btok = col >> 11, key = col & 2047;
        const int kt = key >> 6, kw = key & 63;
        const size_t addr = ((size_t)((btok * 16 + hh2) * 32 + kt) << 12)
                          + (((d >> 5) * 4 + (kw >> 4)) << 9)
                          + ((((kw >> 3) & 1) << 5) + (d & 31)) * 8 + (kw & 7);
        PT[addr] = (bf16)v;
      }
    }
}

// ---------------------------------------------------------------------------
// MFMA flash attention, block-level LDS-staged K/V (m97 structure).
// R7 lesson: register-resident K/V prefetch (172 VGPR) forced the compiler
// to sink loads to their uses -> ~16 x 300cyc exposed L2 latency per iter.
// Fix: global_load_lds DMA (zero VGPRs, truly async) from the frag-ordered
// tiles -- each DMA inst is a contiguous 1KB burst (this is what R4 lacked).
// Double-buffered; the compiler's vmcnt(0)-before-barrier drain is exactly
// the kt-tile dependency (kt+1 DMA issues after the barrier). 4 waves share
// one copy per tile (4x less global traffic). sP stays wave-private.
// XCD swizzle + complementary qt pairing as R7.
// ---------------------------------------------------------------------------
__global__ __launch_bounds__(256)
void attn_mfma(const bf16* __restrict__ Qh, const bf16* __restrict__ Ql,
               const bf16* __restrict__ Kt, const bf16* __restrict__ Vt,
               bf16* __restrict__ Omh, bf16* __restrict__ Oml) {
  const int t = threadIdx.x, w = t >> 6, lane = t & 63;
  const int ln31 = lane & 31, half = lane >> 5;
  const int bid = blockIdx.x;
  const int bh = ((bid >> 3) & 3) * 8 + (bid & 7);   // bid%8 == bh%8 -> XCD
  const int qi = bid >> 5;                           // 0..15
  const int qt = (qi < 8) ? qi : 23 - qi;            // complementary pairing
  const int i0 = qt * 128;
  const int b = bh >> 4, h = bh & 15;
  const int i0w = i0 + w * 32;                 // this wave's first q row
  const int lim = i0w + WIN;                   // allowed: j <= lim + rl

  __shared__ bf16 sK[2][8 * 512];              // K tile dbuf (8KB each)
  __shared__ bf16 sV[2][8 * 512];              // V tile dbuf
  __shared__ bf16 sP[128 * 72];                // wave-private rows

  // ---- Q fragments: hi+lo combined, scaled by log2(e)/8, re-split ----
  bf16x8 qh[4], ql[4];
  {
    const size_t rowQ = (size_t)(b * SEQ + i0w + ln31);
#pragma unroll
    for (int ks = 0; ks < 4; ++ks) {
      bf16x8 vh = *(const bf16x8*)(Qh + rowQ * 1024 + h * 64 + ks * 16 + half * 8);
      bf16x8 vl = *(const bf16x8*)(Ql + rowQ * 1024 + h * 64 + ks * 16 + half * 8);
#pragma unroll
      for (int j = 0; j < 8; ++j) {
        float f = ((float)vh[j] + (float)vl[j]) * 0.1803368801111204f;  // log2(e)/8
        bf16 hh = (bf16)f;
        qh[ks][j] = hh;
        ql[ks][j] = (bf16)(f - (float)hh);
      }
    }
  }
  bf16x8 onesf;
#pragma unroll
  for (int j = 0; j < 8; ++j) onesf[j] = (ln31 == 0) ? (bf16)1.0f : (bf16)0.0f;

  f32x16 accO0, accO1, accL;
#pragma unroll
  for (int r = 0; r < 16; ++r) { accO0[r] = 0.f; accO1[r] = 0.f; accL[r] = 0.f; }

  // per-(b,h) tile bases; each tile is 4096 els, frag-slot ordered
  const bf16* KtBH = Kt + ((size_t)(b * 16 + h) << 17);
  const bf16* VtBH = Vt + ((size_t)(b * 16 + h) << 17);
  const int lane8 = lane * 8;

  const int nkt_b = min((i0 + 127 + WIN) / 64 + 1, SEQ / 64);   // block tiles
  const int nkt_w = min((i0w + 31 + WIN) / 64 + 1, SEQ / 64);   // wave tiles

  // stage tile kt into buffer bsel: 16 contiguous-1KB DMAs, 4 per wave
  auto stage = [&](int kt, int bsel) {
    const size_t toff = ((size_t)kt << 12) + lane8;
#pragma unroll
    for (int ii = 0; ii < 4; ++ii) {
      const int s = w * 4 + ii;            // 0..15
      if (s < 8) {
        GLOAD_LDS(KtBH + toff + (s << 9), &sK[bsel][s << 9]);
      } else {
        const int sv = s - 8;
        GLOAD_LDS(VtBH + toff + (sv << 9), &sV[bsel][sv << 9]);
      }
    }
  };

  auto compute = [&](int kt, const bf16* Kb, const bf16* Vb) {
    const int j0 = kt * 64;

    // ---- S = Q K^T (Q split: hh + lh), K frags from LDS ----
    f32x16 S0, S1;
#pragma unroll
    for (int r = 0; r < 16; ++r) { S0[r] = 0.f; S1[r] = 0.f; }
#pragma unroll
    for (int ks = 0; ks < 4; ++ks) {
      bf16x8 k0 = *(const bf16x8*)&Kb[(ks << 9) + lane8];
      bf16x8 k1 = *(const bf16x8*)&Kb[((4 + ks) << 9) + lane8];
      S0 = __builtin_amdgcn_mfma_f32_32x32x16_bf16(qh[ks], k0, S0, 0, 0, 0);
      S0 = __builtin_amdgcn_mfma_f32_32x32x16_bf16(ql[ks], k0, S0, 0, 0, 0);
      S1 = __builtin_amdgcn_mfma_f32_32x32x16_bf16(qh[ks], k1, S1, 0, 0, 0);
      S1 = __builtin_amdgcn_mfma_f32_32x32x16_bf16(ql[ks], k1, S1, 0, 0, 0);
    }

    // ---- softmax: p = exp2(s); mask -> 0 after exp; write P to LDS ----
#pragma unroll
    for (int c = 0; c < 2; ++c) {
      f32x16& S = c ? S1 : S0;
      const int vj = j0 + c * 32 + ln31 - lim;        // mask if vj > rl
      const bool may = (j0 + c * 32 + 31) > lim;
#pragma unroll
      for (int r = 0; r < 16; ++r) {
        const int rl = (r & 3) + 8 * (r >> 2) + 4 * half;
        float pv = fast_exp2(S[r]);
        if (may && (vj > rl)) pv = 0.f;
        sP[(w * 32 + rl) * 72 + c * 32 + ln31] = (bf16)pv;
      }
    }

    // ---- O += P V ; l += P 1  (wave-private P rows; V frags from LDS) ----
#pragma unroll
    for (int ks = 0; ks < 4; ++ks) {
      bf16x8 pA = *(const bf16x8*)&sP[(w * 32 + ln31) * 72 + ks * 16 + half * 8];
      bf16x8 v0 = *(const bf16x8*)&Vb[(ks << 9) + lane8];
      bf16x8 v1 = *(const bf16x8*)&Vb[((4 + ks) << 9) + lane8];
      accO0 = __builtin_amdgcn_mfma_f32_32x32x16_bf16(pA, v0, accO0, 0, 0, 0);
      accO1 = __builtin_amdgcn_mfma_f32_32x32x16_bf16(pA, v1, accO1, 0, 0, 0);
      accL  = __builtin_amdgcn_mfma_f32_32x32x16_bf16(pA, onesf, accL, 0, 0, 0);
    }
  };

  stage(0, 0);
  for (int kt = 0; kt < nkt_b; ++kt) {
    __syncthreads();   // drains kt's DMA (vmcnt0) + frees other buffer
    if (kt + 1 < nkt_b) stage(kt + 1, (kt + 1) & 1);
    if (kt < nkt_w) {  // wave-uniform tail skip
      if (kt & 1) compute(kt, sK[1], sV[1]);
      else        compute(kt, sK[0], sV[0]);
    }
  }

  // ---- epilogue: O /= l, write Om hi/lo ----
#pragma unroll
  for (int r = 0; r < 16; ++r) {
    const int rl = (r & 3) + 8 * (r >> 2) + 4 * half;
    const float lv = __shfl(accL[r], lane & 32, 64);
    const float inv = 1.0f / lv;
    const size_t grow = (size_t)(b * SEQ + i0w + rl);
    const int col0 = h * 64 + ln31;
    const float v0 = accO0[r] * inv;
    const float v1 = accO1[r] * inv;
    const bf16 h0 = (bf16)v0, h1 = (bf16)v1;
    Omh[grow * DMODEL + col0]      = h0;
    Oml[grow * DMODEL + col0]      = (bf16)(v0 - (float)h0);
    Omh[grow * DMODEL + col0 + 32] = h1;
    Oml[grow * DMODEL + col0 + 32] = (bf16)(v1 - (float)h1);
  }
}

// ---------------------------------------------------------------------------
extern "C" void kernel_launch(void* const* d_in, const int* in_sizes, int n_in,
                              void* d_out, int out_size, void* d_ws, size_t ws_size,
                              hipStream_t stream) {
  const float* x  = (const float*)d_in[0];
  const float* w1 = (const float*)d_in[1];
  const float* b1 = (const float*)d_in[2];
  const float* w2 = (const float*)d_in[3];
  const float* b2 = (const float*)d_in[4];
  float* out = (float*)d_out;

  char* ws = (char*)d_ws;
  bf16* Qh   = (bf16*)(ws + 0);          // [4096][1024]
  bf16* Ql   = (bf16*)(ws + 8388608);    // [4096][1024]
  bf16* Kt   = (bf16*)(ws + 16777216);   // frag-order tiles, 8 MB
  bf16* Vt   = (bf16*)(ws + 25165824);   // frag-order tiles, 8 MB
  bf16* xh   = (bf16*)(ws + 33554432);   // [4096][1024]
  bf16* xl   = (bf16*)(ws + 41943040);
  bf16* w1h  = (bf16*)(ws + 50331648);   // [3072][1024]
  bf16* w1l  = (bf16*)(ws + 56623104);
  bf16* w2h  = (bf16*)(ws + 62914560);   // [1024][1024]
  bf16* w2l  = (bf16*)(ws + 65011712);
  bf16* Omh  = xh;                       // reuse (x dead after V^T gemm)
  bf16* Oml  = xl;

  cvt_all<<<dim3(4096), 256, 0, stream>>>(x, w1, w2, xh, xl, w1h, w1l, w2h, w2l);

  // Q (hi+lo, 3 MFMA) and K (frag tiles, 1 MFMA): x @ w1[0:2048]^T + b1
  gemm_split<<<dim3(2048 / 128, MTOT / 128), 256, 0, stream>>>(
      xh, xl, w1h, w1l, b1, DMODEL, 2048, 1, nullptr, Qh, Ql, Kt);

  // V^T frag tiles: w1[2048:3072] @ x^T + b1[2048:] (row bias), hh-only
  gemm_hh_v<<<dim3(MTOT / 128, DMODEL / 128), 256, 0, stream>>>(
      w1h + 2048 * 1024, xh, b1 + 2048, DMODEL, MTOT, Vt);

  attn_mfma<<<dim3(512), 256, 0, stream>>>(Qh, Ql, Kt, Vt, Omh, Oml);

  // out = Om @ w2^T + b2 (fp32)
  gemm_split<<<dim3(DMODEL / 128, MTOT / 128), 256, 0, stream>>>(
      Omh, Oml, w2h, w2l, b2, DMODEL, DMODEL, 0, out, nullptr, nullptr, nullptr);
}